// Round 1
// baseline (104.425 us; speedup 1.0000x reference)
//
#include <hip/hip_runtime.h>
#include <hip/hip_bf16.h>

// GeneralizedRecallLoss: scores (512, 8192) f32, k_vals (3,) i32, pos_num=16.
// Output: single f32 scalar (mean smooth-recall loss).
//
// Math per row b:
//   pos = scores[b, :16]; neg = scores[b, 16:]
//   rank[j] = 1 + #{i != j : pos[i] >= pos[j]}
//             + sum_n f(neg[n] - pos[j] + 0.1)
//   f(d) = d>=0 ? softplus(d/0.1) + 0.1 : softplus(d/0.01)
//        = lin + log1p(exp(-|t|)),  t = d*(d>=0?10:100), lin = d>=0? t+0.1 : 0
//   recall[j,k] = logaddexp(0, min((rank[j]-k)*10, 88))
//   out = mean_b ( sum_{j,k} recall / (16*3) )

#define POSN 16
#define NK 3
#define BLOCK 256

__global__ __launch_bounds__(BLOCK)
void recall_loss_kernel(const float* __restrict__ scores,
                        const int* __restrict__ k_vals,
                        float* __restrict__ out,
                        int ncols, int nrows) {
    const int b = blockIdx.x;
    const int tid = threadIdx.x;
    const float* row = scores + (size_t)b * ncols;

    __shared__ float s_pos[POSN];
    __shared__ float s_part[BLOCK / 64][POSN];

    if (tid < POSN) s_pos[tid] = row[tid];
    __syncthreads();

    // broadcast pos into registers (compile-time indexed)
    float pos[POSN];
#pragma unroll
    for (int j = 0; j < POSN; ++j) pos[j] = s_pos[j];

    float acc[POSN];
#pragma unroll
    for (int j = 0; j < POSN; ++j) acc[j] = 0.0f;

    const int nneg = ncols - POSN;
    for (int n = tid; n < nneg; n += BLOCK) {
        const float nm = row[POSN + n] + 0.1f;   // neg + NEG_MARGIN
#pragma unroll
        for (int j = 0; j < POSN; ++j) {
            float d  = nm - pos[j];
            bool  ge = (d >= 0.0f);
            // t = d * (ge ? 10 : 100); arg = -|t| * log2(e)
            float c   = ge ? -14.4269504089f : -144.269504089f;  // -scale*log2e
            float arg = c * fabsf(d);
            float e   = exp2f(arg);                  // v_exp_f32
            float l   = __log2f(1.0f + e);           // v_log_f32
            float lin = ge ? __fmaf_rn(d, 10.0f, 0.1f) : 0.0f;
            acc[j] += lin;
            acc[j] = __fmaf_rn(l, 0.69314718056f, acc[j]);
        }
    }

    // reduce 16 accumulators across the wave (64 lanes)
#pragma unroll
    for (int j = 0; j < POSN; ++j) {
        float v = acc[j];
        v += __shfl_down(v, 32);
        v += __shfl_down(v, 16);
        v += __shfl_down(v, 8);
        v += __shfl_down(v, 4);
        v += __shfl_down(v, 2);
        v += __shfl_down(v, 1);
        acc[j] = v;
    }
    const int wave = tid >> 6;
    const int lane = tid & 63;
    if (lane == 0) {
#pragma unroll
        for (int j = 0; j < POSN; ++j) s_part[wave][j] = acc[j];
    }
    __syncthreads();

    if (tid < POSN) {
        const int j = tid;
        float negsum = 0.0f;
#pragma unroll
        for (int w = 0; w < BLOCK / 64; ++w) negsum += s_part[w][j];

        // pos_term: count of i (incl. i==j, then subtract the diagonal)
        const float pj = s_pos[j];
        float cnt = 0.0f;
#pragma unroll
        for (int i = 0; i < POSN; ++i) cnt += (s_pos[i] >= pj) ? 1.0f : 0.0f;
        cnt -= 1.0f;  // remove i==j (eye)

        const float rank = 1.0f + cnt + negsum;

        float rsum = 0.0f;
#pragma unroll
        for (int k = 0; k < NK; ++k) {
            float z = (rank - (float)k_vals[k]) * 10.0f;
            z = fminf(z, 88.0f);
            // logaddexp(0, z) = max(z,0) + log1p(exp(-|z|))
            float e = exp2f(-1.44269504089f * fabsf(z));
            rsum += fmaxf(z, 0.0f) + 0.69314718056f * __log2f(1.0f + e);
        }

        // reduce the 16 values (lanes 0..15 of wave 0)
        rsum += __shfl_down(rsum, 8);
        rsum += __shfl_down(rsum, 4);
        rsum += __shfl_down(rsum, 2);
        rsum += __shfl_down(rsum, 1);
        if (j == 0) {
            const float scale = 1.0f / ((float)POSN * (float)NK * (float)nrows);
            atomicAdd(out, rsum * scale);
        }
    }
}

extern "C" void kernel_launch(void* const* d_in, const int* in_sizes, int n_in,
                              void* d_out, int out_size, void* d_ws, size_t ws_size,
                              hipStream_t stream) {
    const float* scores = (const float*)d_in[0];
    const int*   k_vals = (const int*)d_in[1];
    // d_in[2] = pos_num (16) — layout is compile-time POSN here.
    float* out = (float*)d_out;

    const int nrows = 512;
    const int ncols = in_sizes[0] / nrows;  // 8192

    hipMemsetAsync(out, 0, sizeof(float), stream);  // d_out is poisoned each call
    recall_loss_kernel<<<nrows, BLOCK, 0, stream>>>(scores, k_vals, out, ncols, nrows);
}

// Round 2
// 97.008 us; speedup vs baseline: 1.0765x; 1.0765x over previous
//
#include <hip/hip_runtime.h>
#include <hip/hip_bf16.h>

// GeneralizedRecallLoss: scores (512, 8192) f32, k_vals (3,) i32, pos_num=16.
// Output: single f32 scalar.
//
// Stage 1 (negsum_kernel): 512 rows x 4 chunks blocks; each wave owns 4 of the
//   16 j's and scans its chunk's negs. Writes partial negsum to ws[c][row][j].
// Stage 2 (finalize_kernel): 512x16 (row,j) items -> rank -> 3 recalls ->
//   block reduce -> atomicAdd into d_out.
//
// Math per pair (d = neg - pos[j] + 0.1):
//   f(d) = max(t,0) + 0.1*[t>=0] + log1p(exp(-|t|)), t = d*(d>=0?10:100)
// With t10' = 10*log2e*d: exp arg = min(-t10', 10*t10') (since t100' = 10*t10'),
// linear part = [t10'>=0] * (t10'*ln2 + 0.1), log part = ln2*log2(1+2^arg).

#define ROWS 512
#define COLS 8192
#define POSN 16
#define NK 3
#define NCHUNK 4
#define NEG_PER_CHUNK 2044   // (8192-16)/4
#define NF4 511              // float4s per chunk

__global__ __launch_bounds__(256)
void negsum_kernel(const float* __restrict__ scores, float* __restrict__ ws)
{
    const int b     = blockIdx.x;
    const int row   = b >> 2;
    const int chunk = b & 3;
    const int wave  = threadIdx.x >> 6;
    const int lane  = threadIdx.x & 63;
    const float* rowp = scores + (size_t)row * COLS;

    const float C10 = 14.4269504089f;     // 10*log2(e)
    const float A0  = 1.44269504089f;     // 0.1*C10
    const float LN2 = 0.69314718056f;

    // this wave's 4 pos values, pre-scaled
    float p10[4];
#pragma unroll
    for (int jj = 0; jj < 4; ++jj)
        p10[jj] = rowp[wave * 4 + jj] * C10;

    float acc[4] = {0.0f, 0.0f, 0.0f, 0.0f};

    const float4* negs =
        reinterpret_cast<const float4*>(rowp + POSN + chunk * NEG_PER_CHUNK);

#pragma unroll 2
    for (int it = 0; it < 8; ++it) {
        const int f = it * 64 + lane;
        if (f < NF4) {
            const float4 v = negs[f];
            float a10[4];
            a10[0] = __fmaf_rn(v.x, C10, A0);   // (neg+0.1)*10*log2e
            a10[1] = __fmaf_rn(v.y, C10, A0);
            a10[2] = __fmaf_rn(v.z, C10, A0);
            a10[3] = __fmaf_rn(v.w, C10, A0);
#pragma unroll
            for (int e = 0; e < 4; ++e) {
#pragma unroll
                for (int jj = 0; jj < 4; ++jj) {
                    const float t10  = a10[e] - p10[jj];
                    const float t100 = 10.0f * t10;
                    const float arg  = fminf(-t10, t100);     // -|t|*log2e
                    const float ex   = exp2f(arg);
                    const float l    = __log2f(1.0f + ex);
                    float lin        = __fmaf_rn(t10, LN2, 0.1f);
                    lin              = (t10 >= 0.0f) ? lin : 0.0f;
                    acc[jj] += lin;
                    acc[jj]  = __fmaf_rn(l, LN2, acc[jj]);
                }
            }
        }
    }

    // reduce each acc across the wave
#pragma unroll
    for (int jj = 0; jj < 4; ++jj) {
        float s = acc[jj];
#pragma unroll
        for (int off = 32; off > 0; off >>= 1)
            s += __shfl_xor(s, off);
        acc[jj] = s;
    }

    if (lane == 0) {
        float* o = ws + ((size_t)(chunk * ROWS + row)) * POSN + wave * 4;
        o[0] = acc[0]; o[1] = acc[1]; o[2] = acc[2]; o[3] = acc[3];
    }
}

__global__ __launch_bounds__(256)
void finalize_kernel(const float* __restrict__ scores,
                     const float* __restrict__ ws,
                     const int* __restrict__ k_vals,
                     float* __restrict__ out)
{
    const int gid = blockIdx.x * 256 + threadIdx.x;   // 0..8191
    const int row = gid >> 4;
    const int j   = gid & 15;
    const float* rowp = scores + (size_t)row * COLS;

    float negsum = 0.0f;
#pragma unroll
    for (int c = 0; c < NCHUNK; ++c)
        negsum += ws[((size_t)(c * ROWS + row)) * POSN + j];

    const float pj = rowp[j];
    float cnt = -1.0f;                    // remove the i==j diagonal
#pragma unroll
    for (int i = 0; i < POSN; ++i)
        cnt += (rowp[i] >= pj) ? 1.0f : 0.0f;

    const float rank = 1.0f + cnt + negsum;

    float rsum = 0.0f;
#pragma unroll
    for (int k = 0; k < NK; ++k) {
        float z = (rank - (float)k_vals[k]) * 10.0f;
        z = fminf(z, 88.0f);
        // logaddexp(0, z) = max(z,0) + ln2*log2(1 + 2^(-|z|*log2e))
        const float e = exp2f(-1.44269504089f * fabsf(z));
        rsum += fmaxf(z, 0.0f) + 0.69314718056f * __log2f(1.0f + e);
    }

    // block reduce (4 waves)
    const int wave = threadIdx.x >> 6;
    const int lane = threadIdx.x & 63;
#pragma unroll
    for (int off = 32; off > 0; off >>= 1)
        rsum += __shfl_xor(rsum, off);

    __shared__ float sp[4];
    if (lane == 0) sp[wave] = rsum;
    __syncthreads();
    if (threadIdx.x == 0) {
        const float s = sp[0] + sp[1] + sp[2] + sp[3];
        atomicAdd(out, s * (1.0f / ((float)POSN * (float)NK * (float)ROWS)));
    }
}

extern "C" void kernel_launch(void* const* d_in, const int* in_sizes, int n_in,
                              void* d_out, int out_size, void* d_ws, size_t ws_size,
                              hipStream_t stream) {
    const float* scores = (const float*)d_in[0];
    const int*   k_vals = (const int*)d_in[1];
    float* out = (float*)d_out;
    float* ws  = (float*)d_ws;   // 4*512*16 f32 = 128 KB partial neg-sums

    hipMemsetAsync(out, 0, sizeof(float), stream);
    negsum_kernel<<<ROWS * NCHUNK, 256, 0, stream>>>(scores, ws);
    finalize_kernel<<<(ROWS * POSN) / 256, 256, 0, stream>>>(scores, ws, k_vals, out);
}